// Round 4
// baseline (172.250 us; speedup 1.0000x reference)
//
#include <hip/hip_runtime.h>

// Problem constants (from reference): B=4096, N_ELEM=2048, N_NODES=1024, E2=4096
#define B_SAMPLES 4096
#define N_ELEM    2048
#define N_NODES   1024
#define E2        4096
#define BLOCK     256                    // setup / axial kernels
#define MBLOCK    512                    // main kernel block
#define SLOTS     32                     // max entries/node (Poisson mean 4; P(>=32) ~ 1e-15)
#define S         4                      // samples per group
#define NGROUP    (B_SAMPLES / S)        // 1024 sample-groups
#define AX_ELEMS  ((size_t)NGROUP * N_ELEM)   // 2M float4 = 32 MiB

// Workspace layout (bytes):
//   [0, 4K)       : cnt[N_NODES]            (int)
//   [4K, 8K)      : partial[NGROUP]         (float)
//   [8K, 8K+512K) : ell[SLOTS][N_NODES]     (float4 {wx, wy, bitcast(eid), pad})
//   [8K+512K, +32M): ax[NGROUP][N_ELEM]     (float4 = axial of 4 samples)
#define WS_CNT_OFF   0
#define WS_PART_OFF  4096
#define WS_ELL_OFF   8192
#define WS_AX_OFF    (8192 + SLOTS * N_NODES * 16)
#define WS_NEEDED    ((size_t)WS_AX_OFF + AX_ELEMS * 16)

// ---------------------------------------------------------------------------
// Kernel A: ax[g*N_ELEM + e] = {EA[4g+s][e] * e[4g+s][e]}_{s=0..3}.
// Pure streaming: 32 independent coalesced dword loads + 4 coalesced float4
// stores per thread, no barriers, no LDS. First blocks also zero ELL + cnt
// (saves the separate zero launch).
// 2048 blocks x 256: block covers g = blk>>1, e in [ (blk&1)*1024, +1024 ).
// ---------------------------------------------------------------------------
__global__ __launch_bounds__(BLOCK) void neq_axial_kernel(
    const float* __restrict__ EA, const float* __restrict__ e,
    float4* __restrict__ ax, float4* __restrict__ ell, int* __restrict__ cnt)
{
    const int blk = blockIdx.x;
    const int t = threadIdx.x;

    // folded setup: zero ELL table + counters (blocks 0..127 / 0..3)
    {
        int i = blk * BLOCK + t;
        if (i < SLOTS * N_NODES) ell[i] = make_float4(0.f, 0.f, 0.f, 0.f);
        if (i < N_NODES) cnt[i] = 0;
    }

    const int g = blk >> 1;
    const int ebase = (blk & 1) * 1024;
    const int b0 = g * S;
    const float* EAb = EA + (size_t)b0 * N_ELEM + ebase;
    const float* eb  = e  + (size_t)b0 * N_ELEM + ebase;
    float4* outb = ax + (size_t)g * N_ELEM + ebase;

#pragma unroll
    for (int i = 0; i < 4; ++i) {
        const int eoff = t + i * BLOCK;              // 0..1023
        float p0 = EAb[0 * N_ELEM + eoff] * eb[0 * N_ELEM + eoff];
        float p1 = EAb[1 * N_ELEM + eoff] * eb[1 * N_ELEM + eoff];
        float p2 = EAb[2 * N_ELEM + eoff] * eb[2 * N_ELEM + eoff];
        float p3 = EAb[3 * N_ELEM + eoff] * eb[3 * N_ELEM + eoff];
        outb[eoff] = make_float4(p0, p1, p2, p3);
    }
}

// ---------------------------------------------------------------------------
// Setup (fallback path only): zero ELL table + counters.
// ---------------------------------------------------------------------------
__global__ __launch_bounds__(BLOCK) void neq_zero_kernel(
    float4* __restrict__ ell, int* __restrict__ cnt)
{
    const int i = blockIdx.x * BLOCK + threadIdx.x;      // 0 .. 32767
    ell[i] = make_float4(0.f, 0.f, 0.f, 0.f);
    if (i < N_NODES) cnt[i] = 0;
}

// ---------------------------------------------------------------------------
// Build transposed-ELL via global atomics (order-independent sum).
// ---------------------------------------------------------------------------
__global__ __launch_bounds__(BLOCK) void neq_build_kernel(
    const float* __restrict__ vecs, const int* __restrict__ node_ids,
    const int* __restrict__ elem_ids, int* __restrict__ cnt,
    float4* __restrict__ ell)
{
    const int j = blockIdx.x * BLOCK + threadIdx.x;      // 0 .. E2-1
    int nid = node_ids[j];
    int eid = elem_ids[j];
    float2 v = ((const float2*)vecs)[j];
    int slot = atomicAdd(&cnt[nid], 1);                  // device-scope
    if (slot < SLOTS) {
        ell[slot * N_NODES + nid] = make_float4(v.x, v.y, __int_as_float(eid), 0.f);
    }
}

// FMA of a float4 (per-sample) by a scalar weight into a float4 accumulator.
#define FMA4(A, V, W) do { (A).x += (V).x * (W); (A).y += (V).y * (W); \
                           (A).z += (V).z * (W); (A).w += (V).w * (W); } while (0)

// ---------------------------------------------------------------------------
// Kernel B: per-group gather + residual. Stages the precomputed 32 KB ax
// tile (L2/L3-hot, 4 coalesced float4 loads + stride-1 conflict-free b128
// LDS writes), then ELL gather and sum of squares.
// ---------------------------------------------------------------------------
__global__ __launch_bounds__(MBLOCK, 4) void neq_main_kernel(
    const float4* __restrict__ ax,
    const float* __restrict__ q,  const float* __restrict__ r,
    const int* __restrict__ cnt, const float4* __restrict__ ell,
    float* __restrict__ partial)
{
    __shared__ float4 axial4[N_ELEM];    // 32 KiB: axial4[eid] = {s0,s1,s2,s3}
    __shared__ float red[MBLOCK / 64];   // 8

    const int g = blockIdx.x;
    const int b0 = g * S;
    const int t = threadIdx.x;

    // ---- stage ax tile (independent coalesced loads; data just written) ----
    const float4* src = ax + (size_t)g * N_ELEM;
    float4 s0 = src[t];
    float4 s1 = src[t + 512];
    float4 s2 = src[t + 1024];
    float4 s3 = src[t + 1536];

    // per-node counts (thread owns nodes t, t+512)
    int c0n = min(cnt[t], SLOTS);
    int c1n = min(cnt[t + MBLOCK], SLOTS);
    int kmax = max(c0n, c1n);

    axial4[t]        = s0;
    axial4[t + 512]  = s1;
    axial4[t + 1024] = s2;
    axial4[t + 1536] = s3;
    __syncthreads();

    // ---- gather: 2 ELL rows x 2 nodes per iter (zero-padded => branchless) ----
    float4 accx0 = make_float4(0.f, 0.f, 0.f, 0.f);
    float4 accy0 = make_float4(0.f, 0.f, 0.f, 0.f);
    float4 accx1 = make_float4(0.f, 0.f, 0.f, 0.f);
    float4 accy1 = make_float4(0.f, 0.f, 0.f, 0.f);

    for (int k0 = 0; k0 < kmax; k0 += 2) {               // k0+1 <= 31: in-bounds
        const float4* row = ell + (size_t)k0 * N_NODES;
        float4 pk00 = row[t];                            // row k0,   node t
        float4 pk01 = row[t + MBLOCK];                   // row k0,   node t+512
        float4 pk10 = row[N_NODES + t];                  // row k0+1, node t
        float4 pk11 = row[N_NODES + t + MBLOCK];         // row k0+1, node t+512
        float4 ax00 = axial4[__float_as_int(pk00.z)];
        float4 ax01 = axial4[__float_as_int(pk01.z)];
        float4 ax10 = axial4[__float_as_int(pk10.z)];
        float4 ax11 = axial4[__float_as_int(pk11.z)];
        FMA4(accx0, ax00, pk00.x);  FMA4(accy0, ax00, pk00.y);
        FMA4(accx1, ax01, pk01.x);  FMA4(accy1, ax01, pk01.y);
        FMA4(accx0, ax10, pk10.x);  FMA4(accy0, ax10, pk10.y);
        FMA4(accx1, ax11, pk11.x);  FMA4(accy1, ax11, pk11.y);
    }

    // ---- residual & sum of squares (q/r loaded late: low pressure) ----
    float acc = 0.f;
#pragma unroll
    for (int s = 0; s < S; ++s) {
        const float2* q2 = (const float2*)(q + (size_t)(b0 + s) * N_NODES * 2);
        const float2* r2 = (const float2*)(r + (size_t)(b0 + s) * N_NODES * 2);
        float2 qa = q2[t];
        float2 ra = r2[t];
        float2 qb = q2[t + MBLOCK];
        float2 rb = r2[t + MBLOCK];
        float ax0 = (s == 0) ? accx0.x : (s == 1) ? accx0.y : (s == 2) ? accx0.z : accx0.w;
        float ay0 = (s == 0) ? accy0.x : (s == 1) ? accy0.y : (s == 2) ? accy0.z : accy0.w;
        float ax1 = (s == 0) ? accx1.x : (s == 1) ? accx1.y : (s == 2) ? accx1.z : accx1.w;
        float ay1 = (s == 0) ? accy1.x : (s == 1) ? accy1.y : (s == 2) ? accy1.z : accy1.w;
        float x = ax0 - qa.x - ra.x;
        float y = ay0 - qa.y - ra.y;
        acc += x * x + y * y;
        x = ax1 - qb.x - rb.x;
        y = ay1 - qb.y - rb.y;
        acc += x * x + y * y;
    }

    // ---- wave + block reduce ----
#pragma unroll
    for (int off = 32; off > 0; off >>= 1)
        acc += __shfl_down(acc, off, 64);
    if ((t & 63) == 0) red[t >> 6] = acc;
    __syncthreads();
    if (t == 0) {
        float s = 0.f;
#pragma unroll
        for (int w = 0; w < MBLOCK / 64; ++w) s += red[w];
        partial[blockIdx.x] = s;
    }
}

// ---------------------------------------------------------------------------
// Fallback main (R3 form) when ws_size cannot hold the ax buffer.
// ---------------------------------------------------------------------------
__global__ __launch_bounds__(MBLOCK, 4) void neq_main_fallback(
    const float* __restrict__ EA, const float* __restrict__ e,
    const float* __restrict__ q,  const float* __restrict__ r,
    const int* __restrict__ cnt, const float4* __restrict__ ell,
    float* __restrict__ partial)
{
    __shared__ float4 axial4[N_ELEM];
    __shared__ float red[MBLOCK / 64];

    const int b0 = blockIdx.x * S;
    const int t = threadIdx.x;

#pragma unroll
    for (int i = 0; i < N_ELEM / MBLOCK; ++i) {
        int eid = t + i * MBLOCK;
        float4 p;
        const float* EAp = EA + (size_t)b0 * N_ELEM + eid;
        const float* ep  = e  + (size_t)b0 * N_ELEM + eid;
        p.x = EAp[0 * N_ELEM] * ep[0 * N_ELEM];
        p.y = EAp[1 * N_ELEM] * ep[1 * N_ELEM];
        p.z = EAp[2 * N_ELEM] * ep[2 * N_ELEM];
        p.w = EAp[3 * N_ELEM] * ep[3 * N_ELEM];
        axial4[eid] = p;
    }
    int c0n = min(cnt[t], SLOTS);
    int c1n = min(cnt[t + MBLOCK], SLOTS);
    int kmax = max(c0n, c1n);
    __syncthreads();

    float4 accx0 = make_float4(0.f, 0.f, 0.f, 0.f);
    float4 accy0 = make_float4(0.f, 0.f, 0.f, 0.f);
    float4 accx1 = make_float4(0.f, 0.f, 0.f, 0.f);
    float4 accy1 = make_float4(0.f, 0.f, 0.f, 0.f);

    for (int k0 = 0; k0 < kmax; k0 += 2) {
        const float4* row = ell + (size_t)k0 * N_NODES;
        float4 pk00 = row[t];
        float4 pk01 = row[t + MBLOCK];
        float4 pk10 = row[N_NODES + t];
        float4 pk11 = row[N_NODES + t + MBLOCK];
        float4 ax00 = axial4[__float_as_int(pk00.z)];
        float4 ax01 = axial4[__float_as_int(pk01.z)];
        float4 ax10 = axial4[__float_as_int(pk10.z)];
        float4 ax11 = axial4[__float_as_int(pk11.z)];
        FMA4(accx0, ax00, pk00.x);  FMA4(accy0, ax00, pk00.y);
        FMA4(accx1, ax01, pk01.x);  FMA4(accy1, ax01, pk01.y);
        FMA4(accx0, ax10, pk10.x);  FMA4(accy0, ax10, pk10.y);
        FMA4(accx1, ax11, pk11.x);  FMA4(accy1, ax11, pk11.y);
    }

    float acc = 0.f;
#pragma unroll
    for (int s = 0; s < S; ++s) {
        const float2* q2 = (const float2*)(q + (size_t)(b0 + s) * N_NODES * 2);
        const float2* r2 = (const float2*)(r + (size_t)(b0 + s) * N_NODES * 2);
        float2 qa = q2[t];
        float2 ra = r2[t];
        float2 qb = q2[t + MBLOCK];
        float2 rb = r2[t + MBLOCK];
        float ax0 = (s == 0) ? accx0.x : (s == 1) ? accx0.y : (s == 2) ? accx0.z : accx0.w;
        float ay0 = (s == 0) ? accy0.x : (s == 1) ? accy0.y : (s == 2) ? accy0.z : accy0.w;
        float ax1 = (s == 0) ? accx1.x : (s == 1) ? accx1.y : (s == 2) ? accx1.z : accx1.w;
        float ay1 = (s == 0) ? accy1.x : (s == 1) ? accy1.y : (s == 2) ? accy1.z : accy1.w;
        float x = ax0 - qa.x - ra.x;
        float y = ay0 - qa.y - ra.y;
        acc += x * x + y * y;
        x = ax1 - qb.x - rb.x;
        y = ay1 - qb.y - rb.y;
        acc += x * x + y * y;
    }

#pragma unroll
    for (int off = 32; off > 0; off >>= 1)
        acc += __shfl_down(acc, off, 64);
    if ((t & 63) == 0) red[t >> 6] = acc;
    __syncthreads();
    if (t == 0) {
        float s = 0.f;
#pragma unroll
        for (int w = 0; w < MBLOCK / 64; ++w) s += red[w];
        partial[blockIdx.x] = s;
    }
}

// Reduce the per-block partials and apply the mean scale.
__global__ __launch_bounds__(1024) void neq_reduce_kernel(
    const float* __restrict__ partial, float* __restrict__ out)
{
    __shared__ float red[1024 / 64];
    const int t = threadIdx.x;
    float acc = partial[t];                              // NGROUP == 1024
#pragma unroll
    for (int off = 32; off > 0; off >>= 1)
        acc += __shfl_down(acc, off, 64);
    if ((t & 63) == 0) red[t >> 6] = acc;
    __syncthreads();
    if (t == 0) {
        float s = 0.f;
#pragma unroll
        for (int w = 0; w < 1024 / 64; ++w) s += red[w];
        const float inv_n = 1.0f / (float)((size_t)B_SAMPLES * N_NODES * 2);
        out[0] = s * inv_n;
    }
}

extern "C" void kernel_launch(void* const* d_in, const int* in_sizes, int n_in,
                              void* d_out, int out_size, void* d_ws, size_t ws_size,
                              hipStream_t stream) {
    const float* EA       = (const float*)d_in[0];
    const float* e        = (const float*)d_in[1];
    const float* q        = (const float*)d_in[2];
    const float* r        = (const float*)d_in[3];
    const float* vecs     = (const float*)d_in[4];
    const int*   node_ids = (const int*)d_in[5];
    const int*   elem_ids = (const int*)d_in[6];

    char* ws = (char*)d_ws;
    int*    cnt     = (int*)(ws + WS_CNT_OFF);
    float*  partial = (float*)(ws + WS_PART_OFF);
    float4* ell     = (float4*)(ws + WS_ELL_OFF);
    float4* ax      = (float4*)(ws + WS_AX_OFF);

    if (ws_size >= WS_NEEDED) {
        neq_axial_kernel<<<2 * NGROUP, BLOCK, 0, stream>>>(EA, e, ax, ell, cnt);
        neq_build_kernel<<<E2 / BLOCK, BLOCK, 0, stream>>>(
            vecs, node_ids, elem_ids, cnt, ell);
        neq_main_kernel<<<NGROUP, MBLOCK, 0, stream>>>(
            ax, q, r, cnt, ell, partial);
    } else {
        neq_zero_kernel<<<(SLOTS * N_NODES) / BLOCK, BLOCK, 0, stream>>>(ell, cnt);
        neq_build_kernel<<<E2 / BLOCK, BLOCK, 0, stream>>>(
            vecs, node_ids, elem_ids, cnt, ell);
        neq_main_fallback<<<NGROUP, MBLOCK, 0, stream>>>(
            EA, e, q, r, cnt, ell, partial);
    }
    neq_reduce_kernel<<<1, 1024, 0, stream>>>(partial, (float*)d_out);
}

// Round 5
// 161.235 us; speedup vs baseline: 1.0683x; 1.0683x over previous
//
#include <hip/hip_runtime.h>

// Problem constants (from reference): B=4096, N_ELEM=2048, N_NODES=1024, E2=4096
#define B_SAMPLES 4096
#define N_ELEM    2048
#define N_NODES   1024
#define E2        4096
#define BLOCK     256                    // setup kernels
#define MBLOCK    512                    // main kernel block
#define SLOTS     32                     // max entries/node (Poisson mean 4; P(>=32) ~ 1e-15)
#define S         4                      // samples per main block
#define MAIN_BLOCKS (B_SAMPLES / S)      // 1024
#define KFIX      12                     // fixed unrolled ELL rows (wave-max of
                                         // 128 Poisson(4) counts ~ 11-12 anyway)

// Workspace layout (bytes):
//   [0, 4K)        : cnt[N_NODES]          (int)
//   [4K, 4K+512K)  : ell[SLOTS][N_NODES]   (float4 {wx, wy, bitcast(eid), pad})
//   [4K+512K, ...) : partial[MAIN_BLOCKS]  (float)
#define WS_CNT_OFF   0
#define WS_ELL_OFF   4096
#define WS_PART_OFF  (4096 + SLOTS * N_NODES * 16)

// ---------------------------------------------------------------------------
// Setup A: zero ELL table + counters. 128 blocks x 256 = one float4 each.
// ---------------------------------------------------------------------------
__global__ __launch_bounds__(BLOCK) void neq_zero_kernel(
    float4* __restrict__ ell, int* __restrict__ cnt)
{
    const int i = blockIdx.x * BLOCK + threadIdx.x;      // 0 .. 32767
    ell[i] = make_float4(0.f, 0.f, 0.f, 0.f);
    if (i < N_NODES) cnt[i] = 0;
}

// ---------------------------------------------------------------------------
// Setup B: build transposed-ELL via global atomics (order-independent sum).
// ---------------------------------------------------------------------------
__global__ __launch_bounds__(BLOCK) void neq_build_kernel(
    const float* __restrict__ vecs, const int* __restrict__ node_ids,
    const int* __restrict__ elem_ids, int* __restrict__ cnt,
    float4* __restrict__ ell)
{
    const int j = blockIdx.x * BLOCK + threadIdx.x;      // 0 .. E2-1
    int nid = node_ids[j];
    int eid = elem_ids[j];
    float2 v = ((const float2*)vecs)[j];
    int slot = atomicAdd(&cnt[nid], 1);                  // device-scope
    if (slot < SLOTS) {
        ell[slot * N_NODES + nid] = make_float4(v.x, v.y, __int_as_float(eid), 0.f);
    }
}

// FMA of a float4 (per-sample) by a scalar weight into a float4 accumulator.
#define FMA4(A, V, W) do { (A).x += (V).x * (W); (A).y += (V).y * (W); \
                           (A).z += (V).z * (W); (A).w += (V).w * (W); } while (0)

// Gather + accumulate one ELL row pair (node t, node t+512).
#define GFMA(P0, P1) do { \
    float4 gx0 = axial4[__float_as_int((P0).z)]; \
    float4 gx1 = axial4[__float_as_int((P1).z)]; \
    FMA4(accx0, gx0, (P0).x);  FMA4(accy0, gx0, (P0).y); \
    FMA4(accx1, gx1, (P1).x);  FMA4(accy1, gx1, (P1).y); } while (0)

// ---------------------------------------------------------------------------
// Main: one block (512 threads) per S=4 samples.
// Phase 2 is a straight-line burst: KFIX=12 ELL rows x 2 nodes fully
// unrolled as 3 groups of 8 independent dwordx4 loads, with each group's
// loads in flight under the previous group's LDS gathers + FMAs. The old
// dynamic loop already ran every wave to its wave-max kmax (~11-12 for 128
// Poisson(4) nodes), so fixed 12 rows adds no real work. Zero-padded rows
// contribute exactly 0; a rare fixup loop (P ~ 0.8%/wave) covers kmax > 12.
// Ascending-k accumulation order preserved => bitwise-identical result.
// ---------------------------------------------------------------------------
__global__ __launch_bounds__(MBLOCK, 4) void neq_main_kernel(
    const float* __restrict__ EA, const float* __restrict__ e,
    const float* __restrict__ q,  const float* __restrict__ r,
    const int* __restrict__ cnt, const float4* __restrict__ ell,
    float* __restrict__ partial)
{
    __shared__ float4 axial4[N_ELEM];    // 32 KiB: axial4[eid] = {s0,s1,s2,s3}
    __shared__ float red[MBLOCK / 64];   // 8

    const int b0 = blockIdx.x * S;
    const int t = threadIdx.x;

    // ---- phase 1: axial4[eid] = EA*e for 4 samples (coalesced dword loads,
    //      conflict-free stride-1 float4 LDS writes) ----
#pragma unroll
    for (int i = 0; i < N_ELEM / MBLOCK; ++i) {          // 4 iters
        int eid = t + i * MBLOCK;
        float4 p;
        const float* EAp = EA + (size_t)b0 * N_ELEM + eid;
        const float* ep  = e  + (size_t)b0 * N_ELEM + eid;
        p.x = EAp[0 * N_ELEM] * ep[0 * N_ELEM];
        p.y = EAp[1 * N_ELEM] * ep[1 * N_ELEM];
        p.z = EAp[2 * N_ELEM] * ep[2 * N_ELEM];
        p.w = EAp[3 * N_ELEM] * ep[3 * N_ELEM];
        axial4[eid] = p;
    }

    // per-node counts (thread owns nodes t, t+512)
    int c0n = min(cnt[t], SLOTS);
    int c1n = min(cnt[t + MBLOCK], SLOTS);
    int kmax = max(c0n, c1n);
    __syncthreads();

    // ---- phase 2: burst gather ----
    float4 accx0 = make_float4(0.f, 0.f, 0.f, 0.f);
    float4 accy0 = make_float4(0.f, 0.f, 0.f, 0.f);
    float4 accx1 = make_float4(0.f, 0.f, 0.f, 0.f);
    float4 accy1 = make_float4(0.f, 0.f, 0.f, 0.f);

    const float4* e0 = ell + t;                          // node t
    const float4* e1 = ell + t + MBLOCK;                 // node t+512

    // group 0: rows 0-3 (8 independent 16B loads)
    float4 a00 = e0[0 * N_NODES], a01 = e1[0 * N_NODES];
    float4 a10 = e0[1 * N_NODES], a11 = e1[1 * N_NODES];
    float4 a20 = e0[2 * N_NODES], a21 = e1[2 * N_NODES];
    float4 a30 = e0[3 * N_NODES], a31 = e1[3 * N_NODES];

    // group 1: rows 4-7 (in flight under group-0 consume)
    float4 b00 = e0[4 * N_NODES], b01 = e1[4 * N_NODES];
    float4 b10 = e0[5 * N_NODES], b11 = e1[5 * N_NODES];
    float4 b20 = e0[6 * N_NODES], b21 = e1[6 * N_NODES];
    float4 b30 = e0[7 * N_NODES], b31 = e1[7 * N_NODES];

    // consume group 0
    GFMA(a00, a01); GFMA(a10, a11); GFMA(a20, a21); GFMA(a30, a31);

    // group 2: rows 8-11 (in flight under group-1 consume)
    float4 c00 = e0[8 * N_NODES],  c01 = e1[8 * N_NODES];
    float4 c10 = e0[9 * N_NODES],  c11 = e1[9 * N_NODES];
    float4 c20 = e0[10 * N_NODES], c21 = e1[10 * N_NODES];
    float4 c30 = e0[11 * N_NODES], c31 = e1[11 * N_NODES];

    // consume group 1
    GFMA(b00, b01); GFMA(b10, b11); GFMA(b20, b21); GFMA(b30, b31);

    // consume group 2
    GFMA(c00, c01); GFMA(c10, c11); GFMA(c20, c21); GFMA(c30, c31);

    // rare fixup: rows 12 .. kmax-1 (P(any lane needs it) ~ 0.8% per wave)
    for (int k = KFIX; k < kmax; ++k) {
        float4 p0 = e0[(size_t)k * N_NODES];
        float4 p1 = e1[(size_t)k * N_NODES];
        GFMA(p0, p1);
    }

    // ---- phase 3: residual & sum of squares (q/r loaded late: low pressure) ----
    float acc = 0.f;
#pragma unroll
    for (int s = 0; s < S; ++s) {
        const float2* q2 = (const float2*)(q + (size_t)(b0 + s) * N_NODES * 2);
        const float2* r2 = (const float2*)(r + (size_t)(b0 + s) * N_NODES * 2);
        float2 qa = q2[t];
        float2 ra = r2[t];
        float2 qb = q2[t + MBLOCK];
        float2 rb = r2[t + MBLOCK];
        float ax0 = (s == 0) ? accx0.x : (s == 1) ? accx0.y : (s == 2) ? accx0.z : accx0.w;
        float ay0 = (s == 0) ? accy0.x : (s == 1) ? accy0.y : (s == 2) ? accy0.z : accy0.w;
        float ax1 = (s == 0) ? accx1.x : (s == 1) ? accx1.y : (s == 2) ? accx1.z : accx1.w;
        float ay1 = (s == 0) ? accy1.x : (s == 1) ? accy1.y : (s == 2) ? accy1.z : accy1.w;
        float x = ax0 - qa.x - ra.x;
        float y = ay0 - qa.y - ra.y;
        acc += x * x + y * y;
        x = ax1 - qb.x - rb.x;
        y = ay1 - qb.y - rb.y;
        acc += x * x + y * y;
    }

    // ---- wave + block reduce ----
#pragma unroll
    for (int off = 32; off > 0; off >>= 1)
        acc += __shfl_down(acc, off, 64);
    if ((t & 63) == 0) red[t >> 6] = acc;
    __syncthreads();
    if (t == 0) {
        float s = 0.f;
#pragma unroll
        for (int w = 0; w < MBLOCK / 64; ++w) s += red[w];
        partial[blockIdx.x] = s;
    }
}

// Reduce the per-block partials and apply the mean scale.
__global__ __launch_bounds__(1024) void neq_reduce_kernel(
    const float* __restrict__ partial, float* __restrict__ out)
{
    __shared__ float red[1024 / 64];
    const int t = threadIdx.x;
    float acc = partial[t];                              // MAIN_BLOCKS == 1024
#pragma unroll
    for (int off = 32; off > 0; off >>= 1)
        acc += __shfl_down(acc, off, 64);
    if ((t & 63) == 0) red[t >> 6] = acc;
    __syncthreads();
    if (t == 0) {
        float s = 0.f;
#pragma unroll
        for (int w = 0; w < 1024 / 64; ++w) s += red[w];
        const float inv_n = 1.0f / (float)((size_t)B_SAMPLES * N_NODES * 2);
        out[0] = s * inv_n;
    }
}

extern "C" void kernel_launch(void* const* d_in, const int* in_sizes, int n_in,
                              void* d_out, int out_size, void* d_ws, size_t ws_size,
                              hipStream_t stream) {
    const float* EA       = (const float*)d_in[0];
    const float* e        = (const float*)d_in[1];
    const float* q        = (const float*)d_in[2];
    const float* r        = (const float*)d_in[3];
    const float* vecs     = (const float*)d_in[4];
    const int*   node_ids = (const int*)d_in[5];
    const int*   elem_ids = (const int*)d_in[6];

    char* ws = (char*)d_ws;
    int*    cnt     = (int*)(ws + WS_CNT_OFF);
    float4* ell     = (float4*)(ws + WS_ELL_OFF);
    float*  partial = (float*)(ws + WS_PART_OFF);

    neq_zero_kernel<<<(SLOTS * N_NODES) / BLOCK, BLOCK, 0, stream>>>(ell, cnt);
    neq_build_kernel<<<E2 / BLOCK, BLOCK, 0, stream>>>(
        vecs, node_ids, elem_ids, cnt, ell);
    neq_main_kernel<<<MAIN_BLOCKS, MBLOCK, 0, stream>>>(
        EA, e, q, r, cnt, ell, partial);
    neq_reduce_kernel<<<1, 1024, 0, stream>>>(partial, (float*)d_out);
}